// Round 4
// baseline (91.296 us; speedup 1.0000x reference)
//
#include <hip/hip_runtime.h>

#define FLOW_EPS 0.1f

// XOR involution applied to BOTH the global-source float4 index (pre-swizzle)
// and the LDS read index (rule #21: both-sides-or-neither with global_load_lds).
// Keeps gload sources a within-128B permutation (fully coalesced) and makes the
// per-thread stride-9/stride-3 float4 LDS reads bank-balanced.
#define SWZ(f) ((f) ^ (((f) >> 4) & 7))

#define WAITVM(n) asm volatile("s_waitcnt vmcnt(" #n ")" ::: "memory")

#define GLOBAL_AS const __attribute__((address_space(1))) void*
#define LDS_AS __attribute__((address_space(3))) void*

__device__ __forceinline__ void flow_compute(const float* wl, const float* bl,
                                             float& z0, float& z1, float& z2,
                                             float& ld)
{
#pragma unroll
    for (int k = 0; k < 4; ++k) {
        const int o = k * 9;
        const float w00 = wl[o + 0], w01 = wl[o + 1], w02 = wl[o + 2];
        const float w10 = wl[o + 3], w11 = wl[o + 4], w12 = wl[o + 5];
        const float w20 = wl[o + 6], w21 = wl[o + 7], w22 = wl[o + 8];

        const float d0 = fabsf(w00) + FLOW_EPS;
        const float d1 = fabsf(w11) + FLOW_EPS;
        const float d2 = fabsf(w22) + FLOW_EPS;

        // t = z @ L (unit lower-tri), s = t * d, z = s @ U + b (unit upper-tri)
        const float t0 = fmaf(z2, w20, fmaf(z1, w10, z0));
        const float t1 = fmaf(z2, w21, z1);
        const float t2 = z2;
        const float s0 = t0 * d0;
        const float s1 = t1 * d1;
        const float s2 = t2 * d2;
        z0 = s0 + bl[k * 3 + 0];
        z1 = fmaf(s0, w01, s1) + bl[k * 3 + 1];
        z2 = fmaf(s0, w02, fmaf(s1, w12, s2)) + bl[k * 3 + 2];

        // log|EPS + raw diag| — exactly as the TF source
        ld += __logf(fabsf(FLOW_EPS + w00))
            + __logf(fabsf(FLOW_EPS + w11))
            + __logf(fabsf(FLOW_EPS + w22));
    }
}

// Persistent kernel: 2 waves/block, each wave streams independent 64-element
// chunks with double-buffered per-wave LDS and counted vmcnt. NO barriers.
__global__ __launch_bounds__(128) void graphflow_persistent(
    const float* __restrict__ z_in,
    const float* __restrict__ w_in,
    const float* __restrict__ b_in,
    float* __restrict__ out,
    int nchunks, int nwaves)
{
    // per wave, per buffer: w 9x64 f4, b 3x64 f4, z 48 f4  -> 51 KiB/block
    __shared__ float4 lds_w[2][2][576];
    __shared__ float4 lds_b[2][2][192];
    __shared__ float4 lds_z[2][2][48];

    const int wave = threadIdx.x >> 6;
    const int lane = threadIdx.x & 63;
    const int gwave = blockIdx.x * 2 + wave;

    if (gwave >= nchunks) return;  // no barriers in kernel -> early return safe
    const int myn = (nchunks - gwave + nwaves - 1) / nwaves;

    const float4* wv = reinterpret_cast<const float4*>(w_in);
    const float4* bv = reinterpret_cast<const float4*>(b_in);
    const float4* zv = reinterpret_cast<const float4*>(z_in);
    float4* ov = reinterpret_cast<float4*>(out);

    // Issue 13 global_load_lds for one chunk into buffer `sel`.
    auto issue = [&](long long chunk, int sel) {
        const float4* wg = wv + chunk * 576;  // 64 el * 9 f4
        const float4* bg = bv + chunk * 192;  // 64 el * 3 f4
        const float4* zg = zv + chunk * 48;   // 64 el * 0.75 f4
#pragma unroll
        for (int j = 0; j < 9; ++j) {
            const int q = j * 64 + lane;
            __builtin_amdgcn_global_load_lds(
                (GLOBAL_AS)(wg + SWZ(q)),
                (LDS_AS)(&lds_w[wave][sel][j * 64]), 16, 0, 0);
        }
#pragma unroll
        for (int j = 0; j < 3; ++j) {
            const int q = j * 64 + lane;
            __builtin_amdgcn_global_load_lds(
                (GLOBAL_AS)(bg + SWZ(q)),
                (LDS_AS)(&lds_b[wave][sel][j * 64]), 16, 0, 0);
        }
        if (lane < 48) {  // 768 B of z; still 1 VMEM instr (partial exec)
            __builtin_amdgcn_global_load_lds(
                (GLOBAL_AS)(zg + lane),
                (LDS_AS)(&lds_z[wave][sel][0]), 16, 0, 0);
        }
    };

    issue(gwave, 0);  // prologue: chunk 0 -> buf 0

    for (int k = 0; k < myn; ++k) {
        const long long chunk = (long long)gwave + (long long)k * nwaves;
        const bool hasnext = (k + 1 < myn);
        if (hasnext) issue(chunk + nwaves, (k + 1) & 1);

        // vmcnt ledger (stores count too):
        //  k==0, next:  [13 ld c0][13 ld c1]               -> wait 13
        //  k>=1, next:  [13 ld ck][st k-1][13 ld ck+1](+st)-> wait 14
        //  last, k>0:   [13 ld ck][st k-1]                 -> wait 1
        //  only chunk:  [13 ld c0]                         -> wait 0
        if (k == 0) { if (hasnext) { WAITVM(13); } else { WAITVM(0); } }
        else        { if (hasnext) { WAITVM(14); } else { WAITVM(1); } }
        __builtin_amdgcn_sched_barrier(0);

        const int sel = k & 1;

        float wl[36];
#pragma unroll
        for (int s = 0; s < 9; ++s) {
            const int f = 9 * lane + s;
            const float4 t = lds_w[wave][sel][SWZ(f)];
            wl[4 * s + 0] = t.x; wl[4 * s + 1] = t.y;
            wl[4 * s + 2] = t.z; wl[4 * s + 3] = t.w;
        }
        float bl[12];
#pragma unroll
        for (int s = 0; s < 3; ++s) {
            const int f = 3 * lane + s;
            const float4 t = lds_b[wave][sel][SWZ(f)];
            bl[4 * s + 0] = t.x; bl[4 * s + 1] = t.y;
            bl[4 * s + 2] = t.z; bl[4 * s + 3] = t.w;
        }
        const float* zf = reinterpret_cast<const float*>(&lds_z[wave][sel][0]);
        float z0 = zf[3 * lane + 0];  // bank = 3*lane % 32: conflict-free
        float z1 = zf[3 * lane + 1];
        float z2 = zf[3 * lane + 2];

        float ld = 0.0f;
        flow_compute(wl, bl, z0, z1, z2, ld);

        ov[chunk * 64 + lane] = make_float4(z0, z1, z2, ld);
    }
}

// Tail: elements beyond the last full 64-chunk (not hit for B = 2^21).
__global__ __launch_bounds__(256) void graphflow_tail_kernel(
    const float* __restrict__ z_in,
    const float* __restrict__ w_in,
    const float* __restrict__ b_in,
    float* __restrict__ out,
    int start, int B)
{
    const int i = start + blockIdx.x * blockDim.x + threadIdx.x;
    if (i >= B) return;

    const float4* wv = reinterpret_cast<const float4*>(w_in) + (size_t)i * 9;
    const float4* bv = reinterpret_cast<const float4*>(b_in) + (size_t)i * 3;

    float wl[36];
#pragma unroll
    for (int j = 0; j < 9; ++j) {
        float4 t = wv[j];
        wl[j * 4 + 0] = t.x; wl[j * 4 + 1] = t.y;
        wl[j * 4 + 2] = t.z; wl[j * 4 + 3] = t.w;
    }
    float bl[12];
#pragma unroll
    for (int j = 0; j < 3; ++j) {
        float4 t = bv[j];
        bl[j * 4 + 0] = t.x; bl[j * 4 + 1] = t.y;
        bl[j * 4 + 2] = t.z; bl[j * 4 + 3] = t.w;
    }

    float z0 = z_in[(size_t)i * 3 + 0];
    float z1 = z_in[(size_t)i * 3 + 1];
    float z2 = z_in[(size_t)i * 3 + 2];
    float ld = 0.0f;
    flow_compute(wl, bl, z0, z1, z2, ld);
    reinterpret_cast<float4*>(out)[i] = make_float4(z0, z1, z2, ld);
}

extern "C" void kernel_launch(void* const* d_in, const int* in_sizes, int n_in,
                              void* d_out, int out_size, void* d_ws, size_t ws_size,
                              hipStream_t stream) {
    const float* z = (const float*)d_in[0];
    const float* w = (const float*)d_in[1];
    const float* b = (const float*)d_in[2];
    float* out = (float*)d_out;

    const int B = in_sizes[0] / 3;   // z is [B,3]
    const int nchunks = B / 64;      // full 64-element chunks

    if (nchunks > 0) {
        const int grid = 768;        // 3 blocks/CU x 256 CU (51 KiB LDS/block)
        const int nwaves = grid * 2;
        graphflow_persistent<<<grid, 128, 0, stream>>>(z, w, b, out,
                                                       nchunks, nwaves);
    }
    const int rem_start = nchunks * 64;
    const int rem = B - rem_start;
    if (rem > 0) {
        graphflow_tail_kernel<<<(rem + 255) / 256, 256, 0, stream>>>(
            z, w, b, out, rem_start, B);
    }
}